// Round 10
// baseline (2922.631 us; speedup 1.0000x reference)
//
#include <hip/hip_runtime.h>
#include <hip/hip_bf16.h>
#include <stdint.h>
#include <math.h>

#define DEV __device__ __forceinline__

typedef __hip_bfloat16 bf16;
typedef __attribute__((ext_vector_type(8))) __bf16 bf16x8;
typedef __attribute__((ext_vector_type(4))) float f32x4;
typedef __attribute__((ext_vector_type(2))) float f32x2;

static constexpr int B_ = 2;
static constexpr int T_ = 4096;
static constexpr int C_ = 2048;
static constexpr int H_ = 32;

// ---------- helpers ----------
DEV void gld_lds16(const void* g, void* l) {
  __builtin_amdgcn_global_load_lds((const __attribute__((address_space(1))) void*)g,
                                   (__attribute__((address_space(3))) void*)l, 16, 0, 0);
}
DEV void gld_lds4(const void* g, void* l) {
  __builtin_amdgcn_global_load_lds((const __attribute__((address_space(1))) void*)g,
                                   (__attribute__((address_space(3))) void*)l, 4, 0, 0);
}
DEV unsigned short f2bfbits(float f) { bf16 h = __float2bfloat16(f); return __builtin_bit_cast(unsigned short, h); }
DEV void store_bf16x4(bf16* p, f32x4 v) {
  ushort4 u;
  u.x = f2bfbits(v.x); u.y = f2bfbits(v.y); u.z = f2bfbits(v.z); u.w = f2bfbits(v.w);
  *reinterpret_cast<ushort4*>(p) = u;
}
DEV float bfbits2f(unsigned short u) {
  unsigned int x = ((unsigned int)u) << 16;
  return __builtin_bit_cast(float, x);
}
DEV float wsum64(float v) {
#pragma unroll
  for (int m = 32; m > 0; m >>= 1) v += __shfl_xor(v, m, 64);
  return v;
}
template<int CTRL>
DEV float dpp_add(float v) {
  int x = __builtin_bit_cast(int, v);
  int y = __builtin_amdgcn_update_dpp(0, x, CTRL, 0xf, 0xf, false);
  return v + __builtin_bit_cast(float, y);
}
// sum across a 16-lane DPP row (lane bits 0..3 vary) — DPP only, NO bpermute
DEV float red16(float v) {
  v = dpp_add<0xB1>(v);    // quad_perm xor1
  v = dpp_add<0x4E>(v);    // quad_perm xor2
  v = dpp_add<0x124>(v);   // row_ror:4
  v = dpp_add<0x128>(v);   // row_ror:8
  return v;
}
// 2 packed bf16 dwords -> 4 f32
DEV f32x4 cvt4(uint2 u) {
  f32x4 o;
  o.x = __builtin_bit_cast(float, u.x << 16);
  o.y = __builtin_bit_cast(float, u.x & 0xFFFF0000u);
  o.z = __builtin_bit_cast(float, u.y << 16);
  o.w = __builtin_bit_cast(float, u.y & 0xFFFF0000u);
  return o;
}

// ================= GEMM core (shared by template + runtime variants) =========
DEV void gemm_body(const bf16* __restrict__ A, const bf16* __restrict__ Bm,
                   void* __restrict__ Cout, const float* __restrict__ ep,
                   int N, int K, long brow, long bcol, int mode,
                   bf16* lA, bf16* lB)
{
  const int tid  = threadIdx.x;
  const int wave = tid >> 6;
  const int lane = tid & 63;
  const int wr = wave >> 1, wc = wave & 1;

  f32x4 acc[4][4];
#pragma unroll
  for (int m = 0; m < 4; ++m)
#pragma unroll
    for (int n = 0; n < 4; ++n)
      acc[m][n] = f32x4{0.f, 0.f, 0.f, 0.f};

  const bf16* pa = A  + (size_t)(brow + wave * 32 + (lane >> 3)) * K + (lane & 7) * 8;
  const bf16* pb = Bm + (size_t)(bcol + wave * 32 + (lane >> 3)) * K + (lane & 7) * 8;

  for (int k0 = 0; k0 < K; k0 += 64) {
#pragma unroll
    for (int i = 0; i < 4; ++i) gld_lds16(pa + (size_t)i * 8 * K, &lA[(wave * 4 + i) * 512]);
#pragma unroll
    for (int i = 0; i < 4; ++i) gld_lds16(pb + (size_t)i * 8 * K, &lB[(wave * 4 + i) * 512]);
    pa += 64; pb += 64;
    __syncthreads();
#pragma unroll
    for (int kk = 0; kk < 2; ++kk) {
      bf16x8 af[4], bfv[4];
#pragma unroll
      for (int m = 0; m < 4; ++m)
        af[m] = *(const bf16x8*)&lA[(wr * 64 + m * 16 + (lane & 15)) * 64 + kk * 32 + (lane >> 4) * 8];
#pragma unroll
      for (int n = 0; n < 4; ++n)
        bfv[n] = *(const bf16x8*)&lB[(wc * 64 + n * 16 + (lane & 15)) * 64 + kk * 32 + (lane >> 4) * 8];
#pragma unroll
      for (int m = 0; m < 4; ++m)
#pragma unroll
        for (int n = 0; n < 4; ++n)
          acc[m][n] = __builtin_amdgcn_mfma_f32_16x16x32_bf16(af[m], bfv[n], acc[m][n], 0, 0, 0);
    }
    __syncthreads();
  }

  const int cr = (lane >> 4) * 4;
  const int cc = lane & 15;
#pragma unroll
  for (int m = 0; m < 4; ++m) {
#pragma unroll
    for (int n = 0; n < 4; ++n) {
#pragma unroll
      for (int j = 0; j < 4; ++j) {
        long gm = brow + wr * 64 + m * 16 + cr + j;
        long gn = bcol + wc * 64 + n * 16 + cc;
        float val = acc[m][n][j];
        switch (mode) {
          case 0: ((float*)Cout)[gm * N + gn] = val; break;
          case 2: ((bf16*)Cout)[gm * N + gn] = __float2bfloat16(val); break;
          case 3: ((bf16*)Cout)[gm * N + gn] = __float2bfloat16(tanhf(val)); break;
          case 4: ((bf16*)Cout)[gm * N + gn] = __float2bfloat16(1.f / (1.f + expf(-val))); break;
          case 7: {
            long b = gm / T_, t = gm % T_;
            ((bf16*)Cout)[((b * (N >> 6) + (gn >> 6)) * T_ + t) * 64 + (gn & 63)] = __float2bfloat16(val);
          } break;
          case 8: {
            float u = ep[gn] + val;                 // w0 + lora
            float w = -log1pf(expf(-u)) - 0.5f;     // -softplus(-u) - 0.5
            float wd = expf(-expf(w));
            long b = gm / T_, t = gm % T_;
            ((float*)Cout)[((b * (N >> 6) + (gn >> 6)) * T_ + t) * 64 + (gn & 63)] = wd;
          } break;
          case 9: {
            float sg = 1.f / (1.f + expf(-(ep[gn] + val)));
            long b = gm / T_, t = gm % T_;
            ((bf16*)Cout)[((b * (N >> 6) + (gn >> 6)) * T_ + t) * 64 + (gn & 63)] = __float2bfloat16(sg);
          } break;
        }
      }
    }
  }
}

template<int MODE>
__global__ __launch_bounds__(256)
void gemm_bt(const bf16* __restrict__ A, const bf16* __restrict__ Bm,
             void* __restrict__ Cout, const float* __restrict__ ep,
             int N, int K, int T4)
{
  __shared__ bf16 lA[128 * 64];
  __shared__ bf16 lB[128 * 64];
  gemm_body(A, Bm, Cout, ep, N, K, (long)blockIdx.x * 128, (long)blockIdx.y * 128,
            MODE, lA, lB);
}

struct GJ { const bf16* A; const bf16* Bm; void* C; const float* ep; int N, K, mode, ytile; };
struct GJ8 { GJ j[8]; };
__global__ __launch_bounds__(256)
void gemm_multi(GJ8 jobs)
{
  __shared__ bf16 lA[128 * 64];
  __shared__ bf16 lB[128 * 64];
  GJ J = jobs.j[blockIdx.z];
  gemm_body(J.A, J.Bm, J.C, J.ep, J.N, J.K, (long)blockIdx.x * 128,
            (long)(blockIdx.y + J.ytile) * 128, J.mode, lA, lB);
}

// ---------- mix4: one pass of x -> 4 token-shift mixes ----------
__global__ __launch_bounds__(256)
void mix4k(const float* __restrict__ x,
           const float* __restrict__ c0, const float* __restrict__ c1,
           const float* __restrict__ c2, const float* __restrict__ c3,
           bf16* __restrict__ o0, bf16* __restrict__ o1,
           bf16* __restrict__ o2, bf16* __restrict__ o3)
{
  size_t e = ((size_t)blockIdx.x * 256 + threadIdx.x) * 4;
  int c = (int)(e & (C_ - 1));
  size_t m = e >> 11;
  f32x4 xc = *(const f32x4*)(x + e);
  f32x4 dx;
  if ((m & (T_ - 1)) == 0) dx = f32x4{0.f, 0.f, 0.f, 0.f} - xc;
  else                     dx = *(const f32x4*)(x + e - C_) - xc;
  store_bf16x4(o0 + e, xc + dx * (*(const f32x4*)(c0 + c)));
  store_bf16x4(o1 + e, xc + dx * (*(const f32x4*)(c1 + c)));
  store_bf16x4(o2 + e, xc + dx * (*(const f32x4*)(c2 + c)));
  store_bf16x4(o3 + e, xc + dx * (*(const f32x4*)(c3 + c)));
}

// ---------- fused weight-cvt (blocks 0..4095) + mix (blocks 4096..20479) ----------
__global__ __launch_bounds__(256)
void cvtmix(const float* __restrict__ W, bf16* __restrict__ WB,
            const float* __restrict__ x, const float* __restrict__ coef,
            bf16* __restrict__ MIX)
{
  if (blockIdx.x < 4096) {
    size_t e = ((size_t)blockIdx.x * 256 + threadIdx.x) * 4;
    store_bf16x4(WB + e, *(const f32x4*)(W + e));
  } else {
    size_t e = ((size_t)(blockIdx.x - 4096) * 256 + threadIdx.x) * 4;
    int c = (int)(e & (C_ - 1));
    size_t m = e >> 11;
    f32x4 xc = *(const f32x4*)(x + e);
    f32x4 xp;
    if ((m & (T_ - 1)) == 0) xp = f32x4{0.f, 0.f, 0.f, 0.f};
    else                     xp = *(const f32x4*)(x + e - C_);
    f32x4 cf = *(const f32x4*)(coef + c);
    store_bf16x4(MIX + e, xc + (xp - xc) * cf);
  }
}

// ---------- f32 -> bf16 weight convert ----------
__global__ __launch_bounds__(256)
void cvt1(const float* __restrict__ s, bf16* __restrict__ d)
{
  size_t e = ((size_t)blockIdx.x * 256 + threadIdx.x) * 4;
  store_bf16x4(d + e, *(const f32x4*)(s + e));
}

// ---------- transpose+pad LoRA weights to [NP][RP] bf16 ----------
struct TPJob { const float* s; bf16* d; int R, Cs, NP, RP; };
struct TP8 { TPJob j[8]; };
__global__ __launch_bounds__(256)
void tpad(TP8 jobs)
{
  TPJob J = jobs.j[blockIdx.y];
  int i = blockIdx.x * 256 + threadIdx.x;
  int tot = J.NP * J.RP;
  if (i >= tot) return;
  int n = i / J.RP, r = i - n * J.RP;
  float v = (n < J.Cs && r < J.R) ? J.s[(size_t)r * J.Cs + n] : 0.f;
  J.d[i] = __float2bfloat16(v);
}

// ---------- prescan: kk-norm, k-adjust, v-mix, bonus scalar; in-place b/kkn ----------
__global__ __launch_bounds__(256)
void prescan2(const bf16* __restrict__ r16, bf16* __restrict__ k16,
              bf16* __restrict__ v16, bf16* __restrict__ ab,      // a_sig_t -> b16
              bf16* __restrict__ vn16,                            // v_sig_t -> kkn16
              const float* __restrict__ vfirst, const float* __restrict__ kkc,
              const float* __restrict__ kac, const float* __restrict__ rk,
              float* __restrict__ sbonus)
{
  const int wid = threadIdx.x >> 6;
  const int lane = threadIdx.x & 63;
  const long id = (long)blockIdx.x * 4 + wid;   // bh*T + t
  const long bh = id >> 12;
  const long t = id & (T_ - 1);
  const long b = bh >> 5, h = bh & (H_ - 1);
  const long mrow = b * T_ + t;
  const int c = (int)(h * 64 + lane);
  const size_t tp = (size_t)id * 64 + lane;
  float k  = __bfloat162float(k16[tp]);
  float v  = __bfloat162float(v16[tp]);
  float r  = __bfloat162float(r16[tp]);
  float a  = __bfloat162float(ab[tp]);
  float vs = __bfloat162float(vn16[tp]);
  float vf = vfirst[mrow * C_ + c];
  float kkv = k * kkc[c];
  float ssum = wsum64(kkv * kkv);
  float kkn = kkv / fmaxf(sqrtf(ssum), 1e-12f);
  float kn = k * (1.f + (a - 1.f) * kac[c]);
  float vn = v + (vf - v) * vs;
  k16[tp] = __float2bfloat16(kn);
  v16[tp] = __float2bfloat16(vn);
  ab[tp]  = __float2bfloat16(kkn * a);   // b = kk * a
  vn16[tp] = __float2bfloat16(kkn);      // scan negates for a_t = -kk
  float bs = wsum64(r * kn * rk[c]);     // bonus scalar per (b,h,t)
  if (lane == 0) sbonus[id] = bs;
}

// ---------- WKV7 sequential scan, v8 = v5 compute + per-wave 10-deep LDS DMA ring -
// 256 blocks x 256 threads, block = (quarter, bh), bid = quarter*64+bh (co-XCD).
// Wave wv owns rows quarter*16 + wv*4..+4; lane = vl*16+kq; f32x4 state; DPP red16.
// Latency buffer moved to LDS: each wave stages its superstep data (1792B: r,k,n,b,v
// bf16 + w f32) via 7x global_load_lds into a private 10-slot ring (zero VGPR cost,
// ~2500cyc lead). 9 VM events/superstep (7 DMA + 2 y-stores); read slot staged 9
// supersteps back has 72 newer events -> s_waitcnt vmcnt(63) suffices steady-state.
// Order per superstep: vmcnt -> ds_read next slot -> consume (lgkm waits) -> stage
// into just-freed slot (no DMA-overwrite-before-read hazard).
struct SS {
  uint2 r0, r1, k0, k1, n0, n1, b0, b1;
  f32x4 w0, w1;
  unsigned short v0, v1;
};
DEV SS rdss(const char* slot, int kq, int row)
{
  SS s;
  s.r0 = *(const uint2*)(slot + 0    + kq * 8);
  s.r1 = *(const uint2*)(slot + 128  + kq * 8);
  s.k0 = *(const uint2*)(slot + 256  + kq * 8);
  s.k1 = *(const uint2*)(slot + 384  + kq * 8);
  s.n0 = *(const uint2*)(slot + 512  + kq * 8);
  s.n1 = *(const uint2*)(slot + 640  + kq * 8);
  s.b0 = *(const uint2*)(slot + 768  + kq * 8);
  s.b1 = *(const uint2*)(slot + 896  + kq * 8);
  s.w0 = *(const f32x4*)(slot + 1024 + kq * 16);
  s.w1 = *(const f32x4*)(slot + 1280 + kq * 16);
  s.v0 = *(const unsigned short*)(slot + 1536 + row * 2);
  s.v1 = *(const unsigned short*)(slot + 1664 + row * 2);
  return s;
}
DEV float dostep(f32x4& S, uint2 ru, uint2 ku, uint2 nu, uint2 bu,
                 f32x4 W, unsigned short vus)
{
  f32x4 R = cvt4(ru), K = cvt4(ku), N = cvt4(nu), Bv = cvt4(bu);
  float vt = bfbits2f(vus);
  f32x2 acc = S.xy * N.xy;
  acc = __builtin_elementwise_fma(S.zw, N.zw, acc);
  float sa = red16(acc.x + acc.y);
  float nsa = -sa;                               // a_t = -kk
  f32x2 ns2 = f32x2{nsa, nsa}, vt2 = f32x2{vt, vt};
  S.xy = __builtin_elementwise_fma(vt2, K.xy,
           __builtin_elementwise_fma(ns2, Bv.xy, S.xy * W.xy));
  S.zw = __builtin_elementwise_fma(vt2, K.zw,
           __builtin_elementwise_fma(ns2, Bv.zw, S.zw * W.zw));
  f32x2 yq = S.xy * R.xy;
  yq = __builtin_elementwise_fma(S.zw, R.zw, yq);
  return red16(yq.x + yq.y);
}
DEV void consume(f32x4& S, const SS& s, bf16* py, int t, int kq)
{
  float y0 = dostep(S, s.r0, s.k0, s.n0, s.b0, s.w0, s.v0);
  if (kq == 0) py[(size_t)t * 64] = __float2bfloat16(y0);
  float y1 = dostep(S, s.r1, s.k1, s.n1, s.b1, s.w1, s.v1);
  if (kq == 0) py[(size_t)(t + 1) * 64] = __float2bfloat16(y1);
}
__global__ __launch_bounds__(256, 2)
void wkv_scan8(const bf16* __restrict__ r16, const float* __restrict__ w32,
               const bf16* __restrict__ k16, const bf16* __restrict__ v16,
               const bf16* __restrict__ n16, const bf16* __restrict__ b16,
               bf16* __restrict__ y16)
{
  __shared__ __align__(16) char lds[4][10][1792];   // 70KB: 4 waves x 10-slot ring
  const int bh = blockIdx.x & 63;        // co-XCD: all quarters of a head share XCD
  const int quarter = blockIdx.x >> 6;
  const int wv = threadIdx.x >> 6;
  const int lane = threadIdx.x & 63;
  const int vl = lane >> 4;
  const int kq = lane & 15;
  const int row = quarter * 16 + wv * 4 + vl;   // 0..63
  const size_t eb = (size_t)bh * (T_ * 64);
  const bf16* pr = r16 + eb;
  const bf16* pk = k16 + eb;
  const bf16* pn = n16 + eb;
  const bf16* pb = b16 + eb;
  const float* pw = w32 + eb;
  const bf16* pv = v16 + eb;
  bf16* py = y16 + eb + row;
  char* ring = &lds[wv][0][0];

  auto stagef = [&](int ss, int p) {
    char* d = ring + p * 1792;
    size_t e2 = (size_t)ss * 128;   // 2 steps x 64 elems
    gld_lds4(pr + e2 + lane * 2, d + 0);
    gld_lds4(pk + e2 + lane * 2, d + 256);
    gld_lds4(pn + e2 + lane * 2, d + 512);
    gld_lds4(pb + e2 + lane * 2, d + 768);
    gld_lds4(pw + e2 + lane,      d + 1024);
    gld_lds4(pw + e2 + 64 + lane, d + 1280);
    gld_lds4(pv + e2 + lane * 2,  d + 1536);
  };

  const int NS = T_ / 2;                        // 2048 supersteps, even

#pragma unroll
  for (int p = 0; p < 10; ++p) stagef(p, p);
  asm volatile("s_waitcnt vmcnt(0)" ::: "memory");   // one-time drain

  f32x4 S = f32x4{0.f, 0.f, 0.f, 0.f};
  SS A = rdss(ring + 0 * 1792, kq, row);
  __builtin_amdgcn_sched_barrier(0);

  int p = 0;   // = ss % 10
  for (int ss = 0; ss < NS; ss += 2) {
    int p1 = p + 1 == 10 ? 0 : p + 1;
    asm volatile("s_waitcnt vmcnt(63)" ::: "memory");
    SS Bq = rdss(ring + p1 * 1792, kq, row);
    __builtin_amdgcn_sched_barrier(0);
    consume(S, A, py, 2 * ss, kq);
    int nx1 = ss + 10 <= NS - 1 ? ss + 10 : NS - 1;
    stagef(nx1, p);

    int p2 = p1 + 1 == 10 ? 0 : p1 + 1;
    asm volatile("s_waitcnt vmcnt(63)" ::: "memory");
    SS Aq = rdss(ring + p2 * 1792, kq, row);
    __builtin_amdgcn_sched_barrier(0);
    consume(S, Bq, py, 2 * ss + 2, kq);
    int nx2 = ss + 11 <= NS - 1 ? ss + 11 : NS - 1;
    stagef(nx2, p1);

    A = Aq;
    p = p2;
  }
}

// ---------- post: GroupNorm + bonus + gate -> bf16 A for output GEMM ----------
__global__ __launch_bounds__(256)
void postk2(const bf16* __restrict__ y16, const bf16* __restrict__ v16,
            const float* __restrict__ sbonus, const bf16* __restrict__ g16,
            const float* __restrict__ lnw, const float* __restrict__ lnb,
            bf16* __restrict__ opre)
{
  const int wid = threadIdx.x >> 6;
  const int lane = threadIdx.x & 63;
  const long id = (long)blockIdx.x * 4 + wid;
  const long bh = id >> 12;
  const long t = id & (T_ - 1);
  const long b = bh >> 5, h = bh & (H_ - 1);
  const long mrow = b * T_ + t;
  const int c = (int)(h * 64 + lane);
  const size_t tp = (size_t)id * 64 + lane;
  float y = __bfloat162float(y16[tp]);
  float mu = wsum64(y) * (1.f / 64.f);
  float d = y - mu;
  float var = wsum64(d * d) * (1.f / 64.f);
  float yn = d * rsqrtf(var + 0.00064f) * lnw[c] + lnb[c];
  float outv = (yn + sbonus[id] * __bfloat162float(v16[tp]))
               * __bfloat162float(g16[mrow * C_ + c]);
  opre[mrow * C_ + c] = __float2bfloat16(outv);
}

// ---------- launch ----------
extern "C" void kernel_launch(void* const* d_in, const int* in_sizes, int n_in,
                              void* d_out, int out_size, void* d_ws, size_t ws_size,
                              hipStream_t stream)
{
  const float* x    = (const float*)d_in[0];
  const float* vfst = (const float*)d_in[1];
  const float* x_r  = (const float*)d_in[2];
  const float* x_w  = (const float*)d_in[3];
  const float* x_k  = (const float*)d_in[4];
  const float* x_v  = (const float*)d_in[5];
  const float* x_a  = (const float*)d_in[6];
  const float* x_g  = (const float*)d_in[7];
  const float* w0   = (const float*)d_in[8];
  const float* w1   = (const float*)d_in[9];
  const float* w2   = (const float*)d_in[10];
  const float* a0   = (const float*)d_in[11];
  const float* a1   = (const float*)d_in[12];
  const float* a2   = (const float*)d_in[13];
  const float* v0   = (const float*)d_in[14];
  const float* v1   = (const float*)d_in[15];
  const float* v2   = (const float*)d_in[16];
  const float* g1   = (const float*)d_in[17];
  const float* g2   = (const float*)d_in[18];
  const float* k_k  = (const float*)d_in[19];
  const float* k_a  = (const float*)d_in[20];
  const float* r_k  = (const float*)d_in[21];
  const float* W_r  = (const float*)d_in[22];
  const float* W_k  = (const float*)d_in[23];
  const float* W_v  = (const float*)d_in[24];
  const float* W_o  = (const float*)d_in[25];
  const float* lnw  = (const float*)d_in[26];
  const float* lnb  = (const float*)d_in[27];

  const size_t MB = 1048576ULL;
  const size_t HK = 524288ULL;
  if (ws_size < 248 * MB) return;   // proven-safe budget

  char* ws = (char*)d_ws;
  // phase A: 4 mixes for LoRA stage-1 (dead after stage-1)
  bf16* xw = (bf16*)(ws + 0 * MB);
  bf16* xa = (bf16*)(ws + 32 * MB);
  bf16* xv = (bf16*)(ws + 64 * MB);
  bf16* xg = (bf16*)(ws + 96 * MB);
  // phase B aliases
  bf16* r16  = (bf16*)(ws + 0 * MB);     // over xw (dead after stage-1)
  bf16* k16  = (bf16*)(ws + 32 * MB);    // over xa
  bf16* v16  = (bf16*)(ws + 64 * MB);    // over xv
  float* w32 = (float*)(ws + 96 * MB);   // f32 decay 96..160 (over xg, dead)
  bf16* opre = (bf16*)(ws + 96 * MB);    // postk out; w32 dead after scan
  bf16* asig = (bf16*)(ws + 160 * MB);   // a_sig_t -> b16 in prescan
  bf16* vsig = (bf16*)(ws + 192 * MB);   // v_sig_t -> kkn16 in prescan
  bf16* w1t = (bf16*)(ws + 224 * MB);
  bf16* a1t = (bf16*)(ws + 224 * MB + HK);
  bf16* v1t = (bf16*)(ws + 225 * MB);
  bf16* g1t = (bf16*)(ws + 225 * MB + HK);
  bf16* w2t = (bf16*)(ws + 226 * MB + HK);
  bf16* a2t = (bf16*)(ws + 227 * MB);
  bf16* v2t = (bf16*)(ws + 227 * MB + HK);
  bf16* g2t = (bf16*)(ws + 228 * MB);
  bf16* h_w = (bf16*)(ws + 229 * MB);
  bf16* h_a = (bf16*)(ws + 231 * MB);
  bf16* h_v = (bf16*)(ws + 233 * MB);
  bf16* h_g = (bf16*)(ws + 235 * MB);
  float* sb = (float*)(ws + 239 * MB);
  bf16* WB  = (bf16*)(ws + 240 * MB);      // 8MB weight-cvt buffer
  bf16* g16 = (bf16*)d_out;                // gate bf16, d_out lower half
  bf16* MIX = (bf16*)((char*)d_out + 32 * MB);
  bf16* y16 = (bf16*)((char*)d_out + 32 * MB); // scan out over dead MIX

  TP8 jobs;
  jobs.j[0] = TPJob{ w1, w1t, 2048,   96,  128, 2048 };
  jobs.j[1] = TPJob{ a1, a1t, 2048,   96,  128, 2048 };
  jobs.j[2] = TPJob{ v1, v1t, 2048,   64,  128, 2048 };
  jobs.j[3] = TPJob{ g1, g1t, 2048,  256,  256, 2048 };
  jobs.j[4] = TPJob{ w2, w2t,   96, 2048, 2048,  128 };
  jobs.j[5] = TPJob{ a2, a2t,   96, 2048, 2048,  128 };
  jobs.j[6] = TPJob{ v2, v2t,   64, 2048, 2048,  128 };
  jobs.j[7] = TPJob{ g2, g2t,  256, 2048, 2048,  256 };
  tpad<<<dim3(2048, 8), 256, 0, stream>>>(jobs);

  // one pass: all 4 LoRA mixes
  mix4k<<<dim3(16384), 256, 0, stream>>>(x, x_w, x_a, x_v, x_g, xw, xa, xv, xg);

  // batched LoRA stage-1 (5 jobs: w,a,v,g-col0,g-col1)
  GJ8 s1j = {};
  s1j.j[0] = GJ{ xw, w1t, h_w, nullptr, 128, 2048, 3, 0 };
  s1j.j[1] = GJ{ xa, a1t, h_a, nullptr, 128, 2048, 2, 0 };
  s1j.j[2] = GJ{ xv, v1t, h_v, nullptr, 128, 2048, 2, 0 };
  s1j.j[3] = GJ{ xg, g1t, h_g, nullptr, 256, 2048, 4, 0 };
  s1j.j[4] = GJ{ xg, g1t, h_g, nullptr, 256, 2048, 4, 1 };
  gemm_multi<<<dim3(64, 1, 5), 256, 0, stream>>>(s1j);

  // batched LoRA stage-2 (4 jobs)
  GJ8 s2j = {};
  s2j.j[0] = GJ{ h_w, w2t, w32,  w0,      2048, 128, 8, 0 };
  s2j.j[1] = GJ{ h_a, a2t, asig, a0,      2048, 128, 9, 0 };
  s2j.j[2] = GJ{ h_v, v2t, vsig, v0,      2048, 128, 9, 0 };
  s2j.j[3] = GJ{ h_g, g2t, g16,  nullptr, 2048, 256, 2, 0 };
  gemm_multi<<<dim3(64, 16, 4), 256, 0, stream>>>(s2j);

  // big projections: fused cvt+mix, then GEMM -> bf16 [B,H,T,64]
  cvtmix<<<dim3(20480), 256, 0, stream>>>(W_r, WB, x, x_r, MIX);
  gemm_bt<7><<<dim3(64, 16), 256, 0, stream>>>(MIX, WB, r16, nullptr, 2048, 2048, T_);
  cvtmix<<<dim3(20480), 256, 0, stream>>>(W_k, WB, x, x_k, MIX);
  gemm_bt<7><<<dim3(64, 16), 256, 0, stream>>>(MIX, WB, k16, nullptr, 2048, 2048, T_);
  cvtmix<<<dim3(20480), 256, 0, stream>>>(W_v, WB, x, x_v, MIX);
  gemm_bt<7><<<dim3(64, 16), 256, 0, stream>>>(MIX, WB, v16, nullptr, 2048, 2048, T_);

  prescan2<<<dim3(65536), 256, 0, stream>>>(r16, k16, v16, asig, vsig,
                                            vfst, k_k, k_a, r_k, sb);
  wkv_scan8<<<dim3(256), 256, 0, stream>>>(r16, w32, k16, v16, vsig, asig, y16);
  postk2<<<dim3(65536), 256, 0, stream>>>(y16, v16, sb, g16, lnw, lnb, opre);

  cvt1<<<dim3(4096), 256, 0, stream>>>(W_o, WB);
  gemm_bt<0><<<dim3(64, 16), 256, 0, stream>>>(opre, WB, (float*)d_out, nullptr, 2048, 2048, 0);
}

// Round 11
// 1896.236 us; speedup vs baseline: 1.5413x; 1.5413x over previous
//
#include <hip/hip_runtime.h>
#include <hip/hip_bf16.h>
#include <stdint.h>
#include <math.h>

#define DEV __device__ __forceinline__

typedef __hip_bfloat16 bf16;
typedef __attribute__((ext_vector_type(8))) __bf16 bf16x8;
typedef __attribute__((ext_vector_type(4))) float f32x4;
typedef __attribute__((ext_vector_type(2))) float f32x2;

static constexpr int B_ = 2;
static constexpr int T_ = 4096;
static constexpr int C_ = 2048;
static constexpr int H_ = 32;

// ---------- helpers ----------
DEV void gld_lds16(const void* g, void* l) {
  __builtin_amdgcn_global_load_lds((const __attribute__((address_space(1))) void*)g,
                                   (__attribute__((address_space(3))) void*)l, 16, 0, 0);
}
DEV unsigned short f2bfbits(float f) { bf16 h = __float2bfloat16(f); return __builtin_bit_cast(unsigned short, h); }
DEV void store_bf16x4(bf16* p, f32x4 v) {
  ushort4 u;
  u.x = f2bfbits(v.x); u.y = f2bfbits(v.y); u.z = f2bfbits(v.z); u.w = f2bfbits(v.w);
  *reinterpret_cast<ushort4*>(p) = u;
}
DEV float bfbits2f(unsigned short u) {
  unsigned int x = ((unsigned int)u) << 16;
  return __builtin_bit_cast(float, x);
}
DEV float wsum64(float v) {
#pragma unroll
  for (int m = 32; m > 0; m >>= 1) v += __shfl_xor(v, m, 64);
  return v;
}
template<int CTRL>
DEV float dpp_add(float v) {
  int x = __builtin_bit_cast(int, v);
  int y = __builtin_amdgcn_update_dpp(0, x, CTRL, 0xf, 0xf, false);
  return v + __builtin_bit_cast(float, y);
}
// sum across a 16-lane DPP row (lane bits 0..3 vary) — DPP only, NO bpermute
DEV float red16(float v) {
  v = dpp_add<0xB1>(v);    // quad_perm xor1
  v = dpp_add<0x4E>(v);    // quad_perm xor2
  v = dpp_add<0x124>(v);   // row_ror:4
  v = dpp_add<0x128>(v);   // row_ror:8
  return v;
}
// interleaved dword -> (lo bf16 as f32, hi bf16 as f32)
DEV float lo16f(unsigned int u) { return __builtin_bit_cast(float, u << 16); }
DEV float hi16f(unsigned int u) { return __builtin_bit_cast(float, u & 0xFFFF0000u); }

// ---------- GEMM: C[m][n] = sum_k A[m][k]*B[n][k], bf16 in, f32 accum ----------
// 128x128 tile, BK=64, 4 waves (2x2), 16x16x32 MFMA, global_load_lds width-16.
// MODE: 0 f32 [M][N]; 2 bf16 flat; 3 bf16 tanh; 4 bf16 sigmoid;
//       7 bf16 transposed [B,H,T,64]; 8 f32 transposed wdec(ep+val);
//       9/10 bf16 transposed sigmoid(ep+val) interleaved slot 0/1;
//       11/12 bf16 transposed interleaved slot 0/1
template<int MODE>
__global__ __launch_bounds__(256)
void gemm_bt(const bf16* __restrict__ A, const bf16* __restrict__ Bm,
             void* __restrict__ Cout, const float* __restrict__ ep,
             int N, int K, int T4)
{
  __shared__ bf16 lA[128 * 64];
  __shared__ bf16 lB[128 * 64];
  const int tid  = threadIdx.x;
  const int wave = tid >> 6;
  const int lane = tid & 63;
  const long brow = (long)blockIdx.x * 128;
  const long bcol = (long)blockIdx.y * 128;
  const int wr = wave >> 1, wc = wave & 1;

  f32x4 acc[4][4];
#pragma unroll
  for (int m = 0; m < 4; ++m)
#pragma unroll
    for (int n = 0; n < 4; ++n)
      acc[m][n] = f32x4{0.f, 0.f, 0.f, 0.f};

  const bf16* pa = A  + (size_t)(brow + wave * 32 + (lane >> 3)) * K + (lane & 7) * 8;
  const bf16* pb = Bm + (size_t)(bcol + wave * 32 + (lane >> 3)) * K + (lane & 7) * 8;

  for (int k0 = 0; k0 < K; k0 += 64) {
#pragma unroll
    for (int i = 0; i < 4; ++i) gld_lds16(pa + (size_t)i * 8 * K, &lA[(wave * 4 + i) * 512]);
#pragma unroll
    for (int i = 0; i < 4; ++i) gld_lds16(pb + (size_t)i * 8 * K, &lB[(wave * 4 + i) * 512]);
    pa += 64; pb += 64;
    __syncthreads();
#pragma unroll
    for (int kk = 0; kk < 2; ++kk) {
      bf16x8 af[4], bfv[4];
#pragma unroll
      for (int m = 0; m < 4; ++m)
        af[m] = *(const bf16x8*)&lA[(wr * 64 + m * 16 + (lane & 15)) * 64 + kk * 32 + (lane >> 4) * 8];
#pragma unroll
      for (int n = 0; n < 4; ++n)
        bfv[n] = *(const bf16x8*)&lB[(wc * 64 + n * 16 + (lane & 15)) * 64 + kk * 32 + (lane >> 4) * 8];
#pragma unroll
      for (int m = 0; m < 4; ++m)
#pragma unroll
        for (int n = 0; n < 4; ++n)
          acc[m][n] = __builtin_amdgcn_mfma_f32_16x16x32_bf16(af[m], bfv[n], acc[m][n], 0, 0, 0);
    }
    __syncthreads();
  }

  const int cr = (lane >> 4) * 4;
  const int cc = lane & 15;
#pragma unroll
  for (int m = 0; m < 4; ++m) {
#pragma unroll
    for (int n = 0; n < 4; ++n) {
#pragma unroll
      for (int j = 0; j < 4; ++j) {
        long gm = brow + wr * 64 + m * 16 + cr + j;
        long gn = bcol + wc * 64 + n * 16 + cc;
        float val = acc[m][n][j];
        if constexpr (MODE == 0) {
          ((float*)Cout)[gm * N + gn] = val;
        } else if constexpr (MODE == 2) {
          ((bf16*)Cout)[gm * N + gn] = __float2bfloat16(val);
        } else if constexpr (MODE == 3) {
          ((bf16*)Cout)[gm * N + gn] = __float2bfloat16(tanhf(val));
        } else if constexpr (MODE == 4) {
          ((bf16*)Cout)[gm * N + gn] = __float2bfloat16(1.f / (1.f + expf(-val)));
        } else {
          long b = gm / T4, t = gm % T4;
          long tidx = ((b * (N >> 6) + (gn >> 6)) * T4 + t) * 64 + (gn & 63);
          if constexpr (MODE == 7) {
            ((bf16*)Cout)[tidx] = __float2bfloat16(val);
          } else if constexpr (MODE == 8) {
            float u = ep[gn] + val;                 // w0 + lora
            float w = -log1pf(expf(-u)) - 0.5f;     // -softplus(-u) - 0.5
            ((float*)Cout)[tidx] = expf(-expf(w));
          } else if constexpr (MODE == 9) {
            float sg = 1.f / (1.f + expf(-(ep[gn] + val)));
            ((bf16*)Cout)[tidx * 2] = __float2bfloat16(sg);
          } else if constexpr (MODE == 10) {
            float sg = 1.f / (1.f + expf(-(ep[gn] + val)));
            ((bf16*)Cout)[tidx * 2 + 1] = __float2bfloat16(sg);
          } else if constexpr (MODE == 11) {
            ((bf16*)Cout)[tidx * 2] = __float2bfloat16(val);
          } else if constexpr (MODE == 12) {
            ((bf16*)Cout)[tidx * 2 + 1] = __float2bfloat16(val);
          }
        }
      }
    }
  }
}

// ---------- single token-shift mix ----------
__global__ __launch_bounds__(256)
void mix1(const float* __restrict__ x, const float* __restrict__ coef,
          bf16* __restrict__ out)
{
  size_t e = ((size_t)blockIdx.x * 256 + threadIdx.x) * 4;
  int c = (int)(e & (C_ - 1));
  size_t m = e >> 11;
  f32x4 xc = *(const f32x4*)(x + e);
  f32x4 xp;
  if ((m & (T_ - 1)) == 0) xp = f32x4{0.f, 0.f, 0.f, 0.f};
  else                     xp = *(const f32x4*)(x + e - C_);
  f32x4 cf = *(const f32x4*)(coef + c);
  store_bf16x4(out + e, xc + (xp - xc) * cf);
}

// ---------- f32 -> bf16 weight convert (4M elems) ----------
__global__ __launch_bounds__(256)
void cvt1(const float* __restrict__ s, bf16* __restrict__ d)
{
  size_t e = ((size_t)blockIdx.x * 256 + threadIdx.x) * 4;
  store_bf16x4(d + e, *(const f32x4*)(s + e));
}

// ---------- transpose+pad LoRA weights to [NP][RP] bf16, dst[n][r]=src[r][n] ----------
struct TPJob { const float* s; bf16* d; int R, Cs, NP, RP; };
struct TP8 { TPJob j[8]; };
__global__ __launch_bounds__(256)
void tpad(TP8 jobs)
{
  TPJob J = jobs.j[blockIdx.y];
  int i = blockIdx.x * 256 + threadIdx.x;
  int tot = J.NP * J.RP;
  if (i >= tot) return;
  int n = i / J.RP, r = i - n * J.RP;
  float v = (n < J.Cs && r < J.R) ? J.s[(size_t)r * J.Cs + n] : 0.f;
  J.d[i] = __float2bfloat16(v);
}

// ---------- prescan: interleaved streams; av16 -> nb16 in place ----------
__global__ __launch_bounds__(256)
void prescan3(bf16* __restrict__ rk,     // [B,H,T,128] interleaved r(0)/k(1); k updated
              bf16* __restrict__ v16,    // [B,H,T,64]; updated in place
              bf16* __restrict__ av,     // interleaved a_sig(0)/v_sig(1) -> kkn(0)/-kkn*a(1)
              const float* __restrict__ vfirst, const float* __restrict__ kkc,
              const float* __restrict__ kac, const float* __restrict__ rkc,
              float* __restrict__ sbonus)
{
  const int wid = threadIdx.x >> 6;
  const int lane = threadIdx.x & 63;
  const long id = (long)blockIdx.x * 4 + wid;   // bh*T + t
  const long bh = id >> 12;
  const long t = id & (T_ - 1);
  const long b = bh >> 5, h = bh & (H_ - 1);
  const long mrow = b * T_ + t;
  const int c = (int)(h * 64 + lane);
  const size_t tp = (size_t)id * 64 + lane;
  const size_t tp2 = tp * 2;
  float r  = __bfloat162float(rk[tp2]);
  float k  = __bfloat162float(rk[tp2 + 1]);
  float a  = __bfloat162float(av[tp2]);
  float vs = __bfloat162float(av[tp2 + 1]);
  float v  = __bfloat162float(v16[tp]);
  float vf = vfirst[mrow * C_ + c];
  float kkv = k * kkc[c];
  float ssum = wsum64(kkv * kkv);
  float kkn = kkv / fmaxf(sqrtf(ssum), 1e-12f);
  float kn = k * (1.f + (a - 1.f) * kac[c]);
  float vn = v + (vf - v) * vs;
  rk[tp2 + 1] = __float2bfloat16(kn);
  v16[tp] = __float2bfloat16(vn);
  av[tp2]     = __float2bfloat16(kkn);            // n (scan: sa = S.n)
  av[tp2 + 1] = __float2bfloat16(-(kkn * a));     // b_neg (scan: +sa*b_neg)
  float bs = wsum64(r * kn * rkc[c]);             // bonus scalar per (b,h,t)
  if (lane == 0) sbonus[id] = bs;
}

// ---------- WKV7 sequential scan, v9 = v5 + interleaved wide loads ----------
// 256 blocks x 256 threads, block = (quarter, bh), bid = quarter*64+bh (co-XCD).
// Wave wv owns rows quarter*16 + wv*4..+4; lane = vl*16+kq; cols [kq*4,kq*4+4);
// f32x4 state; DPP-only red16. Streams rk (r/k interleaved) and nb (kkn/-kkn*a
// interleaved) load as one dwordx4 per step each (VMEM/superstep 12 -> 8).
// Depth-4 register prefetch, static buffer names.
struct SS {
  uint4 rk0, rk1, nb0, nb1;
  f32x4 w0, w1;
  unsigned short v0, v1;
};
DEV SS ldss(const uint4* prk, const uint4* pnb, const f32x4* pw,
            const unsigned short* pv, int ss, int kq, int row)
{
  SS s;
  int i0 = ss * 32 + kq, i1 = i0 + 16;   // 16 uint4 (=16 f32x4 for w) per step
  s.rk0 = prk[i0]; s.rk1 = prk[i1];
  s.nb0 = pnb[i0]; s.nb1 = pnb[i1];
  s.w0 = pw[i0]; s.w1 = pw[i1];
  int j0 = ss * 128 + row;
  s.v0 = pv[j0]; s.v1 = pv[j0 + 64];
  return s;
}
DEV float dostep(f32x4& S, uint4 rk, uint4 nb, f32x4 W, unsigned short vus)
{
  f32x4 R, K, N, Bn;
  R.x = lo16f(rk.x); K.x = hi16f(rk.x);
  R.y = lo16f(rk.y); K.y = hi16f(rk.y);
  R.z = lo16f(rk.z); K.z = hi16f(rk.z);
  R.w = lo16f(rk.w); K.w = hi16f(rk.w);
  N.x = lo16f(nb.x); Bn.x = hi16f(nb.x);
  N.y = lo16f(nb.y); Bn.y = hi16f(nb.y);
  N.z = lo16f(nb.z); Bn.z = hi16f(nb.z);
  N.w = lo16f(nb.w); Bn.w = hi16f(nb.w);
  float vt = bfbits2f(vus);
  f32x2 acc = S.xy * N.xy;
  acc = __builtin_elementwise_fma(S.zw, N.zw, acc);
  float sa = red16(acc.x + acc.y);                // b already negated: use +sa
  f32x2 sa2 = f32x2{sa, sa}, vt2 = f32x2{vt, vt};
  S.xy = __builtin_elementwise_fma(vt2, K.xy,
           __builtin_elementwise_fma(sa2, Bn.xy, S.xy * W.xy));
  S.zw = __builtin_elementwise_fma(vt2, K.zw,
           __builtin_elementwise_fma(sa2, Bn.zw, S.zw * W.zw));
  f32x2 yq = S.xy * R.xy;
  yq = __builtin_elementwise_fma(S.zw, R.zw, yq);
  return red16(yq.x + yq.y);
}
DEV void consume(f32x4& S, const SS& s, bf16* py, int t, int kq)
{
  float y0 = dostep(S, s.rk0, s.nb0, s.w0, s.v0);
  if (kq == 0) py[(size_t)t * 64] = __float2bfloat16(y0);
  float y1 = dostep(S, s.rk1, s.nb1, s.w1, s.v1);
  if (kq == 0) py[(size_t)(t + 1) * 64] = __float2bfloat16(y1);
}
__global__ __launch_bounds__(256, 1)
void wkv_scan9(const bf16* __restrict__ rk16, const float* __restrict__ w32,
               const bf16* __restrict__ nb16, const bf16* __restrict__ v16,
               bf16* __restrict__ y16)
{
  const int bh = blockIdx.x & 63;        // co-XCD: all quarters of a head share XCD
  const int quarter = blockIdx.x >> 6;
  const int wv = threadIdx.x >> 6;
  const int lane = threadIdx.x & 63;
  const int vl = lane >> 4;
  const int kq = lane & 15;
  const int row = quarter * 16 + wv * 4 + vl;   // 0..63
  const size_t eb = (size_t)bh * (T_ * 64);
  const uint4* prk = (const uint4*)(rk16 + eb * 2);
  const uint4* pnb = (const uint4*)(nb16 + eb * 2);
  const f32x4* pw  = (const f32x4*)(w32 + eb);
  const unsigned short* pv = (const unsigned short*)(v16 + eb);
  bf16* py = y16 + eb + row;

  f32x4 S = f32x4{0.f, 0.f, 0.f, 0.f};
  const int NS = T_ / 2;                        // 2048 supersteps, %4 == 0

  SS s0 = ldss(prk, pnb, pw, pv, 0, kq, row);
  SS s1 = ldss(prk, pnb, pw, pv, 1, kq, row);
  SS s2 = ldss(prk, pnb, pw, pv, 2, kq, row);
  SS s3 = ldss(prk, pnb, pw, pv, 3, kq, row);

  for (int ss = 0; ss < NS; ss += 4) {
    int n0 = ss + 4 < NS ? ss + 4 : NS - 1;
    int n1 = ss + 5 < NS ? ss + 5 : NS - 1;
    int n2 = ss + 6 < NS ? ss + 6 : NS - 1;
    int n3 = ss + 7 < NS ? ss + 7 : NS - 1;
    SS p0 = ldss(prk, pnb, pw, pv, n0, kq, row);
    consume(S, s0, py, 2 * ss, kq);
    SS p1 = ldss(prk, pnb, pw, pv, n1, kq, row);
    consume(S, s1, py, 2 * ss + 2, kq);
    SS p2 = ldss(prk, pnb, pw, pv, n2, kq, row);
    consume(S, s2, py, 2 * ss + 4, kq);
    SS p3 = ldss(prk, pnb, pw, pv, n3, kq, row);
    consume(S, s3, py, 2 * ss + 6, kq);
    s0 = p0; s1 = p1; s2 = p2; s3 = p3;
  }
}

// ---------- post: GroupNorm + bonus + gate -> bf16 A for output GEMM ----------
__global__ __launch_bounds__(256)
void postk2(const bf16* __restrict__ y16, const bf16* __restrict__ v16,
            const float* __restrict__ sbonus, const bf16* __restrict__ g16,
            const float* __restrict__ lnw, const float* __restrict__ lnb,
            bf16* __restrict__ opre)
{
  const int wid = threadIdx.x >> 6;
  const int lane = threadIdx.x & 63;
  const long id = (long)blockIdx.x * 4 + wid;
  const long bh = id >> 12;
  const long t = id & (T_ - 1);
  const long b = bh >> 5, h = bh & (H_ - 1);
  const long mrow = b * T_ + t;
  const int c = (int)(h * 64 + lane);
  const size_t tp = (size_t)id * 64 + lane;
  float y = __bfloat162float(y16[tp]);
  float mu = wsum64(y) * (1.f / 64.f);
  float d = y - mu;
  float var = wsum64(d * d) * (1.f / 64.f);
  float yn = d * rsqrtf(var + 0.00064f) * lnw[c] + lnb[c];
  float outv = (yn + sbonus[id] * __bfloat162float(v16[tp]))
               * __bfloat162float(g16[mrow * C_ + c]);
  opre[mrow * C_ + c] = __float2bfloat16(outv);
}

// ---------- launch ----------
extern "C" void kernel_launch(void* const* d_in, const int* in_sizes, int n_in,
                              void* d_out, int out_size, void* d_ws, size_t ws_size,
                              hipStream_t stream)
{
  const float* x    = (const float*)d_in[0];
  const float* vfst = (const float*)d_in[1];
  const float* x_r  = (const float*)d_in[2];
  const float* x_w  = (const float*)d_in[3];
  const float* x_k  = (const float*)d_in[4];
  const float* x_v  = (const float*)d_in[5];
  const float* x_a  = (const float*)d_in[6];
  const float* x_g  = (const float*)d_in[7];
  const float* w0   = (const float*)d_in[8];
  const float* w1   = (const float*)d_in[9];
  const float* w2   = (const float*)d_in[10];
  const float* a0   = (const float*)d_in[11];
  const float* a1   = (const float*)d_in[12];
  const float* a2   = (const float*)d_in[13];
  const float* v0   = (const float*)d_in[14];
  const float* v1   = (const float*)d_in[15];
  const float* v2   = (const float*)d_in[16];
  const float* g1   = (const float*)d_in[17];
  const float* g2   = (const float*)d_in[18];
  const float* k_k  = (const float*)d_in[19];
  const float* k_a  = (const float*)d_in[20];
  const float* r_k  = (const float*)d_in[21];
  const float* W_r  = (const float*)d_in[22];
  const float* W_k  = (const float*)d_in[23];
  const float* W_v  = (const float*)d_in[24];
  const float* W_o  = (const float*)d_in[25];
  const float* lnw  = (const float*)d_in[26];
  const float* lnb  = (const float*)d_in[27];

  const size_t MB = 1048576ULL;
  const size_t HK = 524288ULL;
  if (ws_size < 248 * MB) return;   // proven-safe budget

  char* ws = (char*)d_ws;
  bf16* rk16 = (bf16*)(ws + 0 * MB);     // [B,H,T,128] interleaved r/k
  bf16* v16  = (bf16*)(ws + 64 * MB);    // [B,H,T,64]
  float* w32 = (float*)(ws + 96 * MB);   // [B,H,T,64] f32 decay (96..160)
  bf16* opre = (bf16*)(ws + 96 * MB);    // postk out; w32 dead after scan
  bf16* av16 = (bf16*)(ws + 160 * MB);   // interleaved a_sig/v_sig -> n/b_neg (160..224)
  bf16* w1t = (bf16*)(ws + 224 * MB);
  bf16* a1t = (bf16*)(ws + 224 * MB + HK);
  bf16* v1t = (bf16*)(ws + 225 * MB);
  bf16* g1t = (bf16*)(ws + 225 * MB + HK);
  bf16* w2t = (bf16*)(ws + 226 * MB + HK);
  bf16* a2t = (bf16*)(ws + 227 * MB);
  bf16* v2t = (bf16*)(ws + 227 * MB + HK);
  bf16* g2t = (bf16*)(ws + 228 * MB);      // ends 229MB
  bf16* h_w = (bf16*)(ws + 229 * MB);      // [8192][128] 2MB
  bf16* h_a = (bf16*)(ws + 231 * MB);
  bf16* h_v = (bf16*)(ws + 233 * MB);
  bf16* h_g = (bf16*)(ws + 235 * MB);      // [8192][256] 4MB -> ends 239
  float* sb = (float*)(ws + 239 * MB);     // bonus scalars [B,H,T] 1MB
  bf16* WB  = (bf16*)(ws + 240 * MB);      // 8MB weight-cvt buffer -> ends 248
  bf16* g16 = (bf16*)d_out;                // gate bf16, d_out lower half
  bf16* MIX = (bf16*)((char*)d_out + 32 * MB); // recycled mix buffer
  bf16* y16 = (bf16*)((char*)d_out + 32 * MB); // scan out over dead MIX

  TP8 jobs;
  jobs.j[0] = TPJob{ w1, w1t, 2048,   96,  128, 2048 };
  jobs.j[1] = TPJob{ a1, a1t, 2048,   96,  128, 2048 };
  jobs.j[2] = TPJob{ v1, v1t, 2048,   64,  128, 2048 };
  jobs.j[3] = TPJob{ g1, g1t, 2048,  256,  256, 2048 };
  jobs.j[4] = TPJob{ w2, w2t,   96, 2048, 2048,  128 };
  jobs.j[5] = TPJob{ a2, a2t,   96, 2048, 2048,  128 };
  jobs.j[6] = TPJob{ v2, v2t,   64, 2048, 2048,  128 };
  jobs.j[7] = TPJob{ g2, g2t,  256, 2048, 2048,  256 };
  tpad<<<dim3(2048, 8), 256, 0, stream>>>(jobs);

  // LoRA stage-1 (mix recomputed per GEMM; activation fused)
  mix1<<<dim3(16384), 256, 0, stream>>>(x, x_w, MIX);
  gemm_bt<3><<<dim3(64, 1), 256, 0, stream>>>(MIX, w1t, h_w, nullptr, 128, 2048, 0);
  mix1<<<dim3(16384), 256, 0, stream>>>(x, x_a, MIX);
  gemm_bt<2><<<dim3(64, 1), 256, 0, stream>>>(MIX, a1t, h_a, nullptr, 128, 2048, 0);
  mix1<<<dim3(16384), 256, 0, stream>>>(x, x_v, MIX);
  gemm_bt<2><<<dim3(64, 1), 256, 0, stream>>>(MIX, v1t, h_v, nullptr, 128, 2048, 0);
  mix1<<<dim3(16384), 256, 0, stream>>>(x, x_g, MIX);
  gemm_bt<4><<<dim3(64, 2), 256, 0, stream>>>(MIX, g1t, h_g, nullptr, 256, 2048, 0);

  // LoRA stage-2 (wdec f32 / sigmoids fused, head-transposed; a/v interleaved)
  gemm_bt<8> <<<dim3(64, 16), 256, 0, stream>>>(h_w, w2t, w32,  w0, 2048, 128, T_);
  gemm_bt<9> <<<dim3(64, 16), 256, 0, stream>>>(h_a, a2t, av16, a0, 2048, 128, T_);
  gemm_bt<10><<<dim3(64, 16), 256, 0, stream>>>(h_v, v2t, av16, v0, 2048, 128, T_);
  gemm_bt<2> <<<dim3(64, 16), 256, 0, stream>>>(h_g, g2t, g16, nullptr, 2048, 256, 0);

  // big projections (cvt + mix recycled) -> interleaved rk16, plain v16
  cvt1<<<dim3(4096), 256, 0, stream>>>(W_r, WB);
  mix1<<<dim3(16384), 256, 0, stream>>>(x, x_r, MIX);
  gemm_bt<11><<<dim3(64, 16), 256, 0, stream>>>(MIX, WB, rk16, nullptr, 2048, 2048, T_);
  cvt1<<<dim3(4096), 256, 0, stream>>>(W_k, WB);
  mix1<<<dim3(16384), 256, 0, stream>>>(x, x_k, MIX);
  gemm_bt<12><<<dim3(64, 16), 256, 0, stream>>>(MIX, WB, rk16, nullptr, 2048, 2048, T_);
  cvt1<<<dim3(4096), 256, 0, stream>>>(W_v, WB);
  mix1<<<dim3(16384), 256, 0, stream>>>(x, x_v, MIX);
  gemm_bt<7><<<dim3(64, 16), 256, 0, stream>>>(MIX, WB, v16, nullptr, 2048, 2048, T_);

  prescan3<<<dim3(65536), 256, 0, stream>>>(rk16, v16, av16, vfst, k_k, k_a, r_k, sb);
  wkv_scan9<<<dim3(256), 256, 0, stream>>>(rk16, w32, av16, v16, y16);
  postk2<<<dim3(65536), 256, 0, stream>>>(y16, v16, sb, g16, lnw, lnb, opre);

  cvt1<<<dim3(4096), 256, 0, stream>>>(W_o, WB);
  gemm_bt<0><<<dim3(64, 16), 256, 0, stream>>>(opre, WB, (float*)d_out, nullptr, 2048, 2048, 0);
}

// Round 12
// 1634.204 us; speedup vs baseline: 1.7884x; 1.1603x over previous
//
#include <hip/hip_runtime.h>
#include <hip/hip_bf16.h>
#include <stdint.h>
#include <math.h>

#define DEV __device__ __forceinline__

typedef __hip_bfloat16 bf16;
typedef __attribute__((ext_vector_type(8))) __bf16 bf16x8;
typedef __attribute__((ext_vector_type(4))) float f32x4;
typedef __attribute__((ext_vector_type(2))) float f32x2;
typedef __attribute__((ext_vector_type(4))) unsigned int u32x4;

static constexpr int B_ = 2;
static constexpr int T_ = 4096;
static constexpr int C_ = 2048;
static constexpr int H_ = 32;

// ---------- helpers ----------
DEV void gld_lds16(const void* g, void* l) {
  __builtin_amdgcn_global_load_lds((const __attribute__((address_space(1))) void*)g,
                                   (__attribute__((address_space(3))) void*)l, 16, 0, 0);
}
DEV unsigned short f2bfbits(float f) { bf16 h = __float2bfloat16(f); return __builtin_bit_cast(unsigned short, h); }
DEV void store_bf16x4(bf16* p, f32x4 v) {
  ushort4 u;
  u.x = f2bfbits(v.x); u.y = f2bfbits(v.y); u.z = f2bfbits(v.z); u.w = f2bfbits(v.w);
  *reinterpret_cast<ushort4*>(p) = u;
}
DEV float bfbits2f(unsigned short u) {
  unsigned int x = ((unsigned int)u) << 16;
  return __builtin_bit_cast(float, x);
}
DEV float wsum64(float v) {
#pragma unroll
  for (int m = 32; m > 0; m >>= 1) v += __shfl_xor(v, m, 64);
  return v;
}
template<int CTRL>
DEV float dpp_add(float v) {
  int x = __builtin_bit_cast(int, v);
  int y = __builtin_amdgcn_update_dpp(0, x, CTRL, 0xf, 0xf, false);
  return v + __builtin_bit_cast(float, y);
}
// sum across a 16-lane DPP row (lane bits 0..3 vary) — DPP only, NO bpermute
DEV float red16(float v) {
  v = dpp_add<0xB1>(v);    // quad_perm xor1
  v = dpp_add<0x4E>(v);    // quad_perm xor2
  v = dpp_add<0x124>(v);   // row_ror:4
  v = dpp_add<0x128>(v);   // row_ror:8
  return v;
}
// interleaved dword -> (lo bf16 as f32, hi bf16 as f32)
DEV float lo16f(unsigned int u) { return __builtin_bit_cast(float, u << 16); }
DEV float hi16f(unsigned int u) { return __builtin_bit_cast(float, u & 0xFFFF0000u); }

// ---------- GEMM: C[m][n] = sum_k A[m][k]*B[n][k], bf16 in, f32 accum ----------
// 128x128 tile, BK=64, 4 waves (2x2), 16x16x32 MFMA, global_load_lds width-16.
// MODE: 0 f32 [M][N]; 2 bf16 flat; 3 bf16 tanh; 4 bf16 sigmoid;
//       7 bf16 transposed [B,H,T,64]; 8 f32 transposed wdec(ep+val);
//       9/10 bf16 transposed sigmoid(ep+val) interleaved slot 0/1;
//       11/12 bf16 transposed interleaved slot 0/1
template<int MODE>
__global__ __launch_bounds__(256)
void gemm_bt(const bf16* __restrict__ A, const bf16* __restrict__ Bm,
             void* __restrict__ Cout, const float* __restrict__ ep,
             int N, int K, int T4)
{
  __shared__ bf16 lA[128 * 64];
  __shared__ bf16 lB[128 * 64];
  const int tid  = threadIdx.x;
  const int wave = tid >> 6;
  const int lane = tid & 63;
  const long brow = (long)blockIdx.x * 128;
  const long bcol = (long)blockIdx.y * 128;
  const int wr = wave >> 1, wc = wave & 1;

  f32x4 acc[4][4];
#pragma unroll
  for (int m = 0; m < 4; ++m)
#pragma unroll
    for (int n = 0; n < 4; ++n)
      acc[m][n] = f32x4{0.f, 0.f, 0.f, 0.f};

  const bf16* pa = A  + (size_t)(brow + wave * 32 + (lane >> 3)) * K + (lane & 7) * 8;
  const bf16* pb = Bm + (size_t)(bcol + wave * 32 + (lane >> 3)) * K + (lane & 7) * 8;

  for (int k0 = 0; k0 < K; k0 += 64) {
#pragma unroll
    for (int i = 0; i < 4; ++i) gld_lds16(pa + (size_t)i * 8 * K, &lA[(wave * 4 + i) * 512]);
#pragma unroll
    for (int i = 0; i < 4; ++i) gld_lds16(pb + (size_t)i * 8 * K, &lB[(wave * 4 + i) * 512]);
    pa += 64; pb += 64;
    __syncthreads();
#pragma unroll
    for (int kk = 0; kk < 2; ++kk) {
      bf16x8 af[4], bfv[4];
#pragma unroll
      for (int m = 0; m < 4; ++m)
        af[m] = *(const bf16x8*)&lA[(wr * 64 + m * 16 + (lane & 15)) * 64 + kk * 32 + (lane >> 4) * 8];
#pragma unroll
      for (int n = 0; n < 4; ++n)
        bfv[n] = *(const bf16x8*)&lB[(wc * 64 + n * 16 + (lane & 15)) * 64 + kk * 32 + (lane >> 4) * 8];
#pragma unroll
      for (int m = 0; m < 4; ++m)
#pragma unroll
        for (int n = 0; n < 4; ++n)
          acc[m][n] = __builtin_amdgcn_mfma_f32_16x16x32_bf16(af[m], bfv[n], acc[m][n], 0, 0, 0);
    }
    __syncthreads();
  }

  const int cr = (lane >> 4) * 4;
  const int cc = lane & 15;
#pragma unroll
  for (int m = 0; m < 4; ++m) {
#pragma unroll
    for (int n = 0; n < 4; ++n) {
#pragma unroll
      for (int j = 0; j < 4; ++j) {
        long gm = brow + wr * 64 + m * 16 + cr + j;
        long gn = bcol + wc * 64 + n * 16 + cc;
        float val = acc[m][n][j];
        if constexpr (MODE == 0) {
          ((float*)Cout)[gm * N + gn] = val;
        } else if constexpr (MODE == 2) {
          ((bf16*)Cout)[gm * N + gn] = __float2bfloat16(val);
        } else if constexpr (MODE == 3) {
          ((bf16*)Cout)[gm * N + gn] = __float2bfloat16(tanhf(val));
        } else if constexpr (MODE == 4) {
          ((bf16*)Cout)[gm * N + gn] = __float2bfloat16(1.f / (1.f + expf(-val)));
        } else {
          long b = gm / T4, t = gm % T4;
          long tidx = ((b * (N >> 6) + (gn >> 6)) * T4 + t) * 64 + (gn & 63);
          if constexpr (MODE == 7) {
            ((bf16*)Cout)[tidx] = __float2bfloat16(val);
          } else if constexpr (MODE == 8) {
            float u = ep[gn] + val;                 // w0 + lora
            float w = -log1pf(expf(-u)) - 0.5f;     // -softplus(-u) - 0.5
            ((float*)Cout)[tidx] = expf(-expf(w));
          } else if constexpr (MODE == 9) {
            float sg = 1.f / (1.f + expf(-(ep[gn] + val)));
            ((bf16*)Cout)[tidx * 2] = __float2bfloat16(sg);
          } else if constexpr (MODE == 10) {
            float sg = 1.f / (1.f + expf(-(ep[gn] + val)));
            ((bf16*)Cout)[tidx * 2 + 1] = __float2bfloat16(sg);
          } else if constexpr (MODE == 11) {
            ((bf16*)Cout)[tidx * 2] = __float2bfloat16(val);
          } else if constexpr (MODE == 12) {
            ((bf16*)Cout)[tidx * 2 + 1] = __float2bfloat16(val);
          }
        }
      }
    }
  }
}

// ---------- single token-shift mix ----------
__global__ __launch_bounds__(256)
void mix1(const float* __restrict__ x, const float* __restrict__ coef,
          bf16* __restrict__ out)
{
  size_t e = ((size_t)blockIdx.x * 256 + threadIdx.x) * 4;
  int c = (int)(e & (C_ - 1));
  size_t m = e >> 11;
  f32x4 xc = *(const f32x4*)(x + e);
  f32x4 xp;
  if ((m & (T_ - 1)) == 0) xp = f32x4{0.f, 0.f, 0.f, 0.f};
  else                     xp = *(const f32x4*)(x + e - C_);
  f32x4 cf = *(const f32x4*)(coef + c);
  store_bf16x4(out + e, xc + (xp - xc) * cf);
}

// ---------- f32 -> bf16 weight convert (4M elems) ----------
__global__ __launch_bounds__(256)
void cvt1(const float* __restrict__ s, bf16* __restrict__ d)
{
  size_t e = ((size_t)blockIdx.x * 256 + threadIdx.x) * 4;
  store_bf16x4(d + e, *(const f32x4*)(s + e));
}

// ---------- transpose+pad LoRA weights to [NP][RP] bf16, dst[n][r]=src[r][n] ----------
struct TPJob { const float* s; bf16* d; int R, Cs, NP, RP; };
struct TP8 { TPJob j[8]; };
__global__ __launch_bounds__(256)
void tpad(TP8 jobs)
{
  TPJob J = jobs.j[blockIdx.y];
  int i = blockIdx.x * 256 + threadIdx.x;
  int tot = J.NP * J.RP;
  if (i >= tot) return;
  int n = i / J.RP, r = i - n * J.RP;
  float v = (n < J.Cs && r < J.R) ? J.s[(size_t)r * J.Cs + n] : 0.f;
  J.d[i] = __float2bfloat16(v);
}

// ---------- prescan: interleaved streams; av16 -> nb16 in place ----------
__global__ __launch_bounds__(256)
void prescan3(bf16* __restrict__ rk,     // [B,H,T,128] interleaved r(0)/k(1); k updated
              bf16* __restrict__ v16,    // [B,H,T,64]; updated in place
              bf16* __restrict__ av,     // interleaved a_sig(0)/v_sig(1) -> kkn(0)/-kkn*a(1)
              const float* __restrict__ vfirst, const float* __restrict__ kkc,
              const float* __restrict__ kac, const float* __restrict__ rkc,
              float* __restrict__ sbonus)
{
  const int wid = threadIdx.x >> 6;
  const int lane = threadIdx.x & 63;
  const long id = (long)blockIdx.x * 4 + wid;   // bh*T + t
  const long bh = id >> 12;
  const long t = id & (T_ - 1);
  const long b = bh >> 5, h = bh & (H_ - 1);
  const long mrow = b * T_ + t;
  const int c = (int)(h * 64 + lane);
  const size_t tp = (size_t)id * 64 + lane;
  const size_t tp2 = tp * 2;
  float r  = __bfloat162float(rk[tp2]);
  float k  = __bfloat162float(rk[tp2 + 1]);
  float a  = __bfloat162float(av[tp2]);
  float vs = __bfloat162float(av[tp2 + 1]);
  float v  = __bfloat162float(v16[tp]);
  float vf = vfirst[mrow * C_ + c];
  float kkv = k * kkc[c];
  float ssum = wsum64(kkv * kkv);
  float kkn = kkv / fmaxf(sqrtf(ssum), 1e-12f);
  float kn = k * (1.f + (a - 1.f) * kac[c]);
  float vn = v + (vf - v) * vs;
  rk[tp2 + 1] = __float2bfloat16(kn);
  v16[tp] = __float2bfloat16(vn);
  av[tp2]     = __float2bfloat16(kkn);            // n (scan: sa = S.n)
  av[tp2 + 1] = __float2bfloat16(-(kkn * a));     // b_neg (scan: +sa*b_neg)
  float bs = wsum64(r * kn * rkc[c]);             // bonus scalar per (b,h,t)
  if (lane == 0) sbonus[id] = bs;
}

// ---------- WKV7 sequential scan, v10 = v9 + inline-asm counted-vmcnt pipeline --
// 256 blocks x 256 threads, block = (quarter, bh), bid = quarter*64+bh (co-XCD).
// Wave wv owns rows quarter*16 + wv*4..+4; lane = vl*16+kq; f32x4 state; DPP red16.
// Loads issued via asm volatile global_load (compiler cannot sink/collapse the
// depth-4 pipeline — R6/R7/R11 all showed VGPR=84..88 = collapsed C++ prefetch).
// 8 loads/superstep; unroll-4 named buffers; each buffer's loads are followed by
// exactly 24 newer loads before its consume -> s_waitcnt vmcnt(24) (in-order
// retirement), stores only add newer events (harmless). sched_barrier(0) after
// each waitcnt (rule: reg-only consumers can hoist past volatile waitcnt).
// Tail over-prefetch reads <=4KB into adjacent ws buffers (in-bounds, unused).
struct SSa {
  u32x4 rk0, rk1, nb0, nb1;
  f32x4 w0, w1;
  unsigned int v0, v1;
};
#define GL4(dst, off, base, IMM) \
  asm volatile("global_load_dwordx4 %0, %1, %2 offset:" IMM \
               : "=v"(dst) : "v"(off), "s"(base) : "memory")
#define GLU(dst, off, base, IMM) \
  asm volatile("global_load_ushort %0, %1, %2 offset:" IMM \
               : "=v"(dst) : "v"(off), "s"(base) : "memory")
#define WAIT24() do { asm volatile("s_waitcnt vmcnt(24)" ::: "memory"); \
  __builtin_amdgcn_sched_barrier(0); } while (0)
#define LDGRP(sb, I0, I1, V0I, V1I) do { \
  GL4(sb.rk0, off1, prk, I0); GL4(sb.rk1, off1, prk, I1); \
  GL4(sb.nb0, off1, pnb, I0); GL4(sb.nb1, off1, pnb, I1); \
  GL4(sb.w0,  off1, pw,  I0); GL4(sb.w1,  off1, pw,  I1); \
  GLU(sb.v0,  off2, pv,  V0I); GLU(sb.v1, off2, pv, V1I); \
} while (0)

DEV float dostep(f32x4& S, u32x4 rk, u32x4 nb, f32x4 W, unsigned int vus)
{
  f32x4 R, K, N, Bn;
  R.x = lo16f(rk.x); K.x = hi16f(rk.x);
  R.y = lo16f(rk.y); K.y = hi16f(rk.y);
  R.z = lo16f(rk.z); K.z = hi16f(rk.z);
  R.w = lo16f(rk.w); K.w = hi16f(rk.w);
  N.x = lo16f(nb.x); Bn.x = hi16f(nb.x);
  N.y = lo16f(nb.y); Bn.y = hi16f(nb.y);
  N.z = lo16f(nb.z); Bn.z = hi16f(nb.z);
  N.w = lo16f(nb.w); Bn.w = hi16f(nb.w);
  float vt = __builtin_bit_cast(float, vus << 16);
  f32x2 acc = S.xy * N.xy;
  acc = __builtin_elementwise_fma(S.zw, N.zw, acc);
  float sa = red16(acc.x + acc.y);                // b pre-negated: use +sa
  f32x2 sa2 = f32x2{sa, sa}, vt2 = f32x2{vt, vt};
  S.xy = __builtin_elementwise_fma(vt2, K.xy,
           __builtin_elementwise_fma(sa2, Bn.xy, S.xy * W.xy));
  S.zw = __builtin_elementwise_fma(vt2, K.zw,
           __builtin_elementwise_fma(sa2, Bn.zw, S.zw * W.zw));
  f32x2 yq = S.xy * R.xy;
  yq = __builtin_elementwise_fma(S.zw, R.zw, yq);
  return red16(yq.x + yq.y);
}
DEV void consume(f32x4& S, const SSa& s, bf16* py, int t, int kq)
{
  float y0 = dostep(S, s.rk0, s.nb0, s.w0, s.v0);
  if (kq == 0) py[(size_t)t * 64] = __float2bfloat16(y0);
  float y1 = dostep(S, s.rk1, s.nb1, s.w1, s.v1);
  if (kq == 0) py[(size_t)(t + 1) * 64] = __float2bfloat16(y1);
}
__global__ __launch_bounds__(256, 1)
void wkv_scan10(const bf16* __restrict__ rk16, const float* __restrict__ w32,
                const bf16* __restrict__ nb16, const bf16* __restrict__ v16,
                bf16* __restrict__ y16)
{
  const int bh = blockIdx.x & 63;        // co-XCD: all quarters of a head share XCD
  const int quarter = blockIdx.x >> 6;
  const int wv = threadIdx.x >> 6;
  const int lane = threadIdx.x & 63;
  const int vl = lane >> 4;
  const int kq = lane & 15;
  const int row = quarter * 16 + wv * 4 + vl;   // 0..63
  const size_t eb = (size_t)bh * (T_ * 64);
  const bf16*  prk = rk16 + eb * 2;
  const bf16*  pnb = nb16 + eb * 2;
  const float* pw  = w32 + eb;
  const bf16*  pv  = v16 + eb;
  bf16* py = y16 + eb + row;

  // byte offsets: rk/nb/w share (512*ss + 16*kq); v uses (256*ss + 2*row)
  unsigned int off1 = (unsigned int)(kq * 16);
  unsigned int off2 = (unsigned int)(row * 2);

  f32x4 S = f32x4{0.f, 0.f, 0.f, 0.f};
  const int NS = T_ / 2;                        // 2048 supersteps, %4 == 0

  SSa s0, s1, s2, s3;
  // prologue: supersteps 0..3 at immediates 0/512/1024/1536
  LDGRP(s0, "0",    "256",  "0",   "128");
  LDGRP(s1, "512",  "768",  "256", "384");
  LDGRP(s2, "1024", "1280", "512", "640");
  LDGRP(s3, "1536", "1792", "768", "896");
  off1 += 2048; off2 += 1024;                   // now pointing at superstep 4

  for (int ss = 0; ss < NS; ss += 4) {
    WAIT24();
    consume(S, s0, py, 2 * ss, kq);
    LDGRP(s0, "0",    "256",  "0",   "128");
    WAIT24();
    consume(S, s1, py, 2 * ss + 2, kq);
    LDGRP(s1, "512",  "768",  "256", "384");
    WAIT24();
    consume(S, s2, py, 2 * ss + 4, kq);
    LDGRP(s2, "1024", "1280", "512", "640");
    WAIT24();
    consume(S, s3, py, 2 * ss + 6, kq);
    LDGRP(s3, "1536", "1792", "768", "896");
    off1 += 2048; off2 += 1024;
  }
}

// ---------- post: GroupNorm + bonus + gate -> bf16 A for output GEMM ----------
__global__ __launch_bounds__(256)
void postk2(const bf16* __restrict__ y16, const bf16* __restrict__ v16,
            const float* __restrict__ sbonus, const bf16* __restrict__ g16,
            const float* __restrict__ lnw, const float* __restrict__ lnb,
            bf16* __restrict__ opre)
{
  const int wid = threadIdx.x >> 6;
  const int lane = threadIdx.x & 63;
  const long id = (long)blockIdx.x * 4 + wid;
  const long bh = id >> 12;
  const long t = id & (T_ - 1);
  const long b = bh >> 5, h = bh & (H_ - 1);
  const long mrow = b * T_ + t;
  const int c = (int)(h * 64 + lane);
  const size_t tp = (size_t)id * 64 + lane;
  float y = __bfloat162float(y16[tp]);
  float mu = wsum64(y) * (1.f / 64.f);
  float d = y - mu;
  float var = wsum64(d * d) * (1.f / 64.f);
  float yn = d * rsqrtf(var + 0.00064f) * lnw[c] + lnb[c];
  float outv = (yn + sbonus[id] * __bfloat162float(v16[tp]))
               * __bfloat162float(g16[mrow * C_ + c]);
  opre[mrow * C_ + c] = __float2bfloat16(outv);
}

// ---------- launch ----------
extern "C" void kernel_launch(void* const* d_in, const int* in_sizes, int n_in,
                              void* d_out, int out_size, void* d_ws, size_t ws_size,
                              hipStream_t stream)
{
  const float* x    = (const float*)d_in[0];
  const float* vfst = (const float*)d_in[1];
  const float* x_r  = (const float*)d_in[2];
  const float* x_w  = (const float*)d_in[3];
  const float* x_k  = (const float*)d_in[4];
  const float* x_v  = (const float*)d_in[5];
  const float* x_a  = (const float*)d_in[6];
  const float* x_g  = (const float*)d_in[7];
  const float* w0   = (const float*)d_in[8];
  const float* w1   = (const float*)d_in[9];
  const float* w2   = (const float*)d_in[10];
  const float* a0   = (const float*)d_in[11];
  const float* a1   = (const float*)d_in[12];
  const float* a2   = (const float*)d_in[13];
  const float* v0   = (const float*)d_in[14];
  const float* v1   = (const float*)d_in[15];
  const float* v2   = (const float*)d_in[16];
  const float* g1   = (const float*)d_in[17];
  const float* g2   = (const float*)d_in[18];
  const float* k_k  = (const float*)d_in[19];
  const float* k_a  = (const float*)d_in[20];
  const float* r_k  = (const float*)d_in[21];
  const float* W_r  = (const float*)d_in[22];
  const float* W_k  = (const float*)d_in[23];
  const float* W_v  = (const float*)d_in[24];
  const float* W_o  = (const float*)d_in[25];
  const float* lnw  = (const float*)d_in[26];
  const float* lnb  = (const float*)d_in[27];

  const size_t MB = 1048576ULL;
  const size_t HK = 524288ULL;
  if (ws_size < 248 * MB) return;   // proven-safe budget

  char* ws = (char*)d_ws;
  bf16* rk16 = (bf16*)(ws + 0 * MB);     // [B,H,T,128] interleaved r/k
  bf16* v16  = (bf16*)(ws + 64 * MB);    // [B,H,T,64]
  float* w32 = (float*)(ws + 96 * MB);   // [B,H,T,64] f32 decay (96..160)
  bf16* opre = (bf16*)(ws + 96 * MB);    // postk out; w32 dead after scan
  bf16* av16 = (bf16*)(ws + 160 * MB);   // interleaved a_sig/v_sig -> n/b_neg (160..224)
  bf16* w1t = (bf16*)(ws + 224 * MB);
  bf16* a1t = (bf16*)(ws + 224 * MB + HK);
  bf16* v1t = (bf16*)(ws + 225 * MB);
  bf16* g1t = (bf16*)(ws + 225 * MB + HK);
  bf16* w2t = (bf16*)(ws + 226 * MB + HK);
  bf16* a2t = (bf16*)(ws + 227 * MB);
  bf16* v2t = (bf16*)(ws + 227 * MB + HK);
  bf16* g2t = (bf16*)(ws + 228 * MB);      // ends 229MB
  bf16* h_w = (bf16*)(ws + 229 * MB);      // [8192][128] 2MB
  bf16* h_a = (bf16*)(ws + 231 * MB);
  bf16* h_v = (bf16*)(ws + 233 * MB);
  bf16* h_g = (bf16*)(ws + 235 * MB);      // [8192][256] 4MB -> ends 239
  float* sb = (float*)(ws + 239 * MB);     // bonus scalars [B,H,T] 1MB
  bf16* WB  = (bf16*)(ws + 240 * MB);      // 8MB weight-cvt buffer -> ends 248
  bf16* g16 = (bf16*)d_out;                // gate bf16, d_out lower half
  bf16* MIX = (bf16*)((char*)d_out + 32 * MB); // recycled mix buffer
  bf16* y16 = (bf16*)((char*)d_out + 32 * MB); // scan out over dead MIX

  TP8 jobs;
  jobs.j[0] = TPJob{ w1, w1t, 2048,   96,  128, 2048 };
  jobs.j[1] = TPJob{ a1, a1t, 2048,   96,  128, 2048 };
  jobs.j[2] = TPJob{ v1, v1t, 2048,   64,  128, 2048 };
  jobs.j[3] = TPJob{ g1, g1t, 2048,  256,  256, 2048 };
  jobs.j[4] = TPJob{ w2, w2t,   96, 2048, 2048,  128 };
  jobs.j[5] = TPJob{ a2, a2t,   96, 2048, 2048,  128 };
  jobs.j[6] = TPJob{ v2, v2t,   64, 2048, 2048,  128 };
  jobs.j[7] = TPJob{ g2, g2t,  256, 2048, 2048,  256 };
  tpad<<<dim3(2048, 8), 256, 0, stream>>>(jobs);

  // LoRA stage-1 (mix recomputed per GEMM; activation fused)
  mix1<<<dim3(16384), 256, 0, stream>>>(x, x_w, MIX);
  gemm_bt<3><<<dim3(64, 1), 256, 0, stream>>>(MIX, w1t, h_w, nullptr, 128, 2048, 0);
  mix1<<<dim3(16384), 256, 0, stream>>>(x, x_a, MIX);
  gemm_bt<2><<<dim3(64, 1), 256, 0, stream>>>(MIX, a1t, h_a, nullptr, 128, 2048, 0);
  mix1<<<dim3(16384), 256, 0, stream>>>(x, x_v, MIX);
  gemm_bt<2><<<dim3(64, 1), 256, 0, stream>>>(MIX, v1t, h_v, nullptr, 128, 2048, 0);
  mix1<<<dim3(16384), 256, 0, stream>>>(x, x_g, MIX);
  gemm_bt<4><<<dim3(64, 2), 256, 0, stream>>>(MIX, g1t, h_g, nullptr, 256, 2048, 0);

  // LoRA stage-2 (wdec f32 / sigmoids fused, head-transposed; a/v interleaved)
  gemm_bt<8> <<<dim3(64, 16), 256, 0, stream>>>(h_w, w2t, w32,  w0, 2048, 128, T_);
  gemm_bt<9> <<<dim3(64, 16), 256, 0, stream>>>(h_a, a2t, av16, a0, 2048, 128, T_);
  gemm_bt<10><<<dim3(64, 16), 256, 0, stream>>>(h_v, v2t, av16, v0, 2048, 128, T_);
  gemm_bt<2> <<<dim3(64, 16), 256, 0, stream>>>(h_g, g2t, g16, nullptr, 2048, 256, 0);

  // big projections (cvt + mix recycled) -> interleaved rk16, plain v16
  cvt1<<<dim3(4096), 256, 0, stream>>>(W_r, WB);
  mix1<<<dim3(16384), 256, 0, stream>>>(x, x_r, MIX);
  gemm_bt<11><<<dim3(64, 16), 256, 0, stream>>>(MIX, WB, rk16, nullptr, 2048, 2048, T_);
  cvt1<<<dim3(4096), 256, 0, stream>>>(W_k, WB);
  mix1<<<dim3(16384), 256, 0, stream>>>(x, x_k, MIX);
  gemm_bt<12><<<dim3(64, 16), 256, 0, stream>>>(MIX, WB, rk16, nullptr, 2048, 2048, T_);
  cvt1<<<dim3(4096), 256, 0, stream>>>(W_v, WB);
  mix1<<<dim3(16384), 256, 0, stream>>>(x, x_v, MIX);
  gemm_bt<7><<<dim3(64, 16), 256, 0, stream>>>(MIX, WB, v16, nullptr, 2048, 2048, T_);

  prescan3<<<dim3(65536), 256, 0, stream>>>(rk16, v16, av16, vfst, k_k, k_a, r_k, sb);
  wkv_scan10<<<dim3(256), 256, 0, stream>>>(rk16, w32, av16, v16, y16);
  postk2<<<dim3(65536), 256, 0, stream>>>(y16, v16, sb, g16, lnw, lnb, opre);

  cvt1<<<dim3(4096), 256, 0, stream>>>(W_o, WB);
  gemm_bt<0><<<dim3(64, 16), 256, 0, stream>>>(opre, WB, (float*)d_out, nullptr, 2048, 2048, 0);
}